// Round 1
// baseline (421.283 us; speedup 1.0000x reference)
//
#include <hip/hip_runtime.h>

#define TSEQ 512
#define BSZN 4
#define NH 16
#define NBN 32
#define EMB 1024
#define HD 64
#define TGT 1536
#define MROWS 6144

typedef unsigned short ushort_t;
typedef __bf16 bf8 __attribute__((ext_vector_type(8)));
typedef unsigned short u16x8 __attribute__((ext_vector_type(8)));
typedef float f32x4 __attribute__((ext_vector_type(4)));

__device__ __forceinline__ unsigned short f2bf(float f) {
  unsigned int u = __builtin_bit_cast(unsigned int, f);
  u += 0x7fffu + ((u >> 16) & 1u);
  return (unsigned short)(u >> 16);
}

__device__ __forceinline__ void gload16(const void* g, void* l) {
  __builtin_amdgcn_global_load_lds(
      (const __attribute__((address_space(1))) void*)g,
      (__attribute__((address_space(3))) void*)l, 16, 0, 0);
}

__device__ __forceinline__ f32x4 mfma_bf16(bf8 a, bf8 b, f32x4 c) {
  return __builtin_amdgcn_mfma_f32_16x16x32_bf16(a, b, c, 0, 0, 0);
}

// ---------------- fp32 -> bf16 convert ----------------
__global__ void cvt_kernel(const float* __restrict__ in, ushort_t* __restrict__ out, int n4) {
  int i = blockIdx.x * blockDim.x + threadIdx.x;
  if (i >= n4) return;
  const float4 v = reinterpret_cast<const float4*>(in)[i];
  ushort4 o;
  o.x = f2bf(v.x); o.y = f2bf(v.y); o.z = f2bf(v.z); o.w = f2bf(v.w);
  reinterpret_cast<ushort4*>(out)[i] = o;
}

// ---------------- GEMM: C[M,N] = A[M,K] * B[N,K]^T + bias ----------------
// MODE 0: qkv projection -> scatter into Q(scaled)/K ([bh][t][hd]) and Vt ([bh][hd][t]), bf16
// MODE 1: fp32 C (VM table)
// MODE 2: fp32 C (final output)
template <int MODE>
__global__ __launch_bounds__(256) void gemm_bt(
    const ushort_t* __restrict__ A, const ushort_t* __restrict__ B,
    const float* __restrict__ bias, float* __restrict__ Cf,
    ushort_t* __restrict__ Qo, ushort_t* __restrict__ Ko, ushort_t* __restrict__ Vto,
    int M, int N, int K) {
  __shared__ ushort_t lA[128 * 32];
  __shared__ ushort_t lB[128 * 32];
  const int tid = threadIdx.x;
  const int lane = tid & 63;
  const int wid = tid >> 6;
  const int l15 = lane & 15, l4 = lane >> 4;
  const int bm = blockIdx.y, bn = blockIdx.x;
  const int wm = (wid >> 1) * 64, wn = (wid & 1) * 64;

  f32x4 acc[4][4] = {};

  const int srow = tid >> 2;       // 0..63
  const int scol = (tid & 3) * 8;  // element offset within 32-wide K tile
  const ushort_t* Ag = A + (size_t)(bm * 128 + srow) * K + scol;
  const ushort_t* Bg = B + (size_t)(bn * 128 + srow) * K + scol;
  ushort_t* lAp = &lA[srow * 32 + scol];
  ushort_t* lBp = &lB[srow * 32 + scol];

  for (int kt = 0; kt < K; kt += 32) {
    __syncthreads();
    gload16(Ag + kt, lAp);
    gload16(Ag + kt + (size_t)64 * K, lAp + 64 * 32);
    gload16(Bg + kt, lBp);
    gload16(Bg + kt + (size_t)64 * K, lBp + 64 * 32);
    __syncthreads();
    bf8 af[4], bv[4];
#pragma unroll
    for (int mi = 0; mi < 4; ++mi)
      af[mi] = *reinterpret_cast<const bf8*>(&lA[(wm + mi * 16 + l15) * 32 + l4 * 8]);
#pragma unroll
    for (int ni = 0; ni < 4; ++ni)
      bv[ni] = *reinterpret_cast<const bf8*>(&lB[(wn + ni * 16 + l15) * 32 + l4 * 8]);
#pragma unroll
    for (int mi = 0; mi < 4; ++mi)
#pragma unroll
      for (int ni = 0; ni < 4; ++ni)
        acc[mi][ni] = mfma_bf16(af[mi], bv[ni], acc[mi][ni]);
  }

#pragma unroll
  for (int ni = 0; ni < 4; ++ni) {
    const int col = bn * 128 + wn + ni * 16 + l15;
    const float bc = bias[col];
#pragma unroll
    for (int mi = 0; mi < 4; ++mi) {
      const int row0 = bm * 128 + wm + mi * 16 + l4 * 4;
      f32x4 v = acc[mi][ni];
#pragma unroll
      for (int r = 0; r < 4; ++r) {
        const int row = row0 + r;
        float val = v[r] + bc;
        if (MODE == 0) {
          const int part = col >> 10;
          const int cc = col & 1023;
          const int h = cc >> 6, d = cc & 63;
          const int t = row >> 2, bb = row & 3;
          const int bh = bb * NH + h;
          if (part == 0) {
            Qo[((size_t)bh * TGT + t) * HD + d] = f2bf(val * 0.125f);
          } else if (part == 1) {
            Ko[((size_t)bh * TGT + t) * HD + d] = f2bf(val);
          } else {
            Vto[((size_t)bh * HD + d) * TGT + t] = f2bf(val);
          }
        } else {
          Cf[(size_t)row * N + col] = val;
        }
      }
    }
  }
}

// ---------------- fused attention (main + ngram), flash-style ----------------
// grid: (tile 0..31, bh 0..63, z 0..2)  z=0 main, z=1,2 ngram g=z-1
__global__ __launch_bounds__(256) void attn_kernel(
    const ushort_t* __restrict__ Q, const ushort_t* __restrict__ Kb,
    const ushort_t* __restrict__ Vt, const float* __restrict__ VM,
    const int* __restrict__ ib_main, const int* __restrict__ ib_rel,
    const float* __restrict__ mask_main, const float* __restrict__ mask_ng,
    ushort_t* __restrict__ AT) {
  __shared__ float S[16][516];
  __shared__ ushort_t P[16][520];
  __shared__ float red_m[16], red_s[16], red_r[16];

  const int tile = blockIdx.x;
  const int bh = blockIdx.y;
  const int z = blockIdx.z;
  const int b = bh >> 4, h = bh & 15;
  const int t0 = tile * 16;
  const int tid = threadIdx.x;
  const int lane = tid & 63, wid = tid >> 6;
  const int l15 = lane & 15, l4 = lane >> 4;

  const int g = z - 1;
  const int nchunk = (z == 0) ? 1 : 2;
  const int qrow0 = (z == 0) ? t0 : TSEQ + g * TSEQ + t0;

  if (tid < 16) { red_m[tid] = -1e30f; red_s[tid] = 0.f; }

  const ushort_t* qp = &Q[((size_t)bh * TGT + qrow0 + l15) * HD + l4 * 8];
  bf8 qf0 = *reinterpret_cast<const bf8*>(qp);
  bf8 qf1 = *reinterpret_cast<const bf8*>(qp + 32);

  f32x4 oacc = {};
  const int d0 = wid * 16;

  for (int ch = 0; ch < nchunk; ++ch) {
    const int srow0 = (ch == 0) ? 0 : TSEQ + g * TSEQ;

    // QK^T: this wave covers cols [wid*128, wid*128+128)
#pragma unroll
    for (int ni = 0; ni < 8; ++ni) {
      const int s0 = wid * 128 + ni * 16;
      const ushort_t* kp = &Kb[((size_t)bh * TGT + srow0 + s0 + l15) * HD + l4 * 8];
      bf8 kf0 = *reinterpret_cast<const bf8*>(kp);
      bf8 kf1 = *reinterpret_cast<const bf8*>(kp + 32);
      f32x4 s4 = {};
      s4 = mfma_bf16(qf0, kf0, s4);
      s4 = mfma_bf16(qf1, kf1, s4);
#pragma unroll
      for (int r = 0; r < 4; ++r) S[l4 * 4 + r][s0 + l15] = s4[r];
    }
    __syncthreads();

    // softmax + rel gather + mask: wave owns rows wid*4..wid*4+3
#pragma unroll
    for (int rr = 0; rr < 4; ++rr) {
      const int r = wid * 4 + rr;
      const int tloc = t0 + r;
      const int qglob = qrow0 + r;
      const int* ibrow;
      const float* mrow;
      if (z == 0) {
        ibrow = ib_main + ((size_t)b * TSEQ + tloc) * TSEQ;
        mrow = mask_main + (size_t)tloc * TSEQ;
      } else {
        ibrow = ib_rel + ((size_t)b * TSEQ + tloc) * (2 * TSEQ) + ch * TSEQ;
        mrow = mask_ng + ((size_t)g * TSEQ + tloc) * (2 * TSEQ) + ch * TSEQ;
      }
      const float* vmp = VM + (size_t)(qglob * BSZN + b) * (NBN * NH);
      float vals[8];
      float mx = -1e30f;
#pragma unroll
      for (int j = 0; j < 8; ++j) {
        const int s = lane * 8 + j;
        const float vv = S[r][s] + vmp[ibrow[s] * NH + h] + mrow[s];
        vals[j] = vv;
        mx = fmaxf(mx, vv);
      }
#pragma unroll
      for (int off = 32; off > 0; off >>= 1) mx = fmaxf(mx, __shfl_xor(mx, off));
      const float oldm = red_m[r];
      const float newm = fmaxf(oldm, mx);
      float sum = 0.f;
      u16x8 pv;
#pragma unroll
      for (int j = 0; j < 8; ++j) {
        const float p = __expf(vals[j] - newm);
        sum += p;
        pv[j] = f2bf(p);
      }
      *reinterpret_cast<u16x8*>(&P[r][lane * 8]) = pv;
#pragma unroll
      for (int off = 32; off > 0; off >>= 1) sum += __shfl_xor(sum, off);
      if (lane == 0) {
        const float rsc = (oldm <= -1e30f) ? 0.f : __expf(oldm - newm);
        red_r[r] = rsc;
        red_s[r] = red_s[r] * rsc + sum;
        red_m[r] = newm;
      }
    }
    __syncthreads();

    // rescale + PV: this wave owns d-tile d0 = wid*16
    {
      f32x4 rs;
#pragma unroll
      for (int r = 0; r < 4; ++r) rs[r] = red_r[l4 * 4 + r];
      oacc *= rs;
    }
#pragma unroll
    for (int ks = 0; ks < 16; ++ks) {
      bf8 pa = *reinterpret_cast<const bf8*>(&P[l15][ks * 32 + l4 * 8]);
      bf8 vb = *reinterpret_cast<const bf8*>(
          &Vt[((size_t)bh * HD + d0 + l15) * TGT + srow0 + ks * 32 + l4 * 8]);
      oacc = mfma_bf16(pa, vb, oacc);
    }
    __syncthreads();
  }

#pragma unroll
  for (int r = 0; r < 4; ++r) {
    const int row = l4 * 4 + r;
    const float inv = 1.f / red_s[row];
    const int tout = qrow0 + row;
    AT[((size_t)tout * BSZN + b) * EMB + h * HD + d0 + l15] = f2bf(oacc[r] * inv);
  }
}

extern "C" void kernel_launch(void* const* d_in, const int* in_sizes, int n_in,
                              void* d_out, int out_size, void* d_ws, size_t ws_size,
                              hipStream_t stream) {
  const float* query     = (const float*)d_in[0];
  const float* mask_main = (const float*)d_in[1];
  const float* mask_ng   = (const float*)d_in[2];
  const int*   ib_main   = (const int*)d_in[3];
  const int*   ib_rel    = (const int*)d_in[4];
  const float* w_in      = (const float*)d_in[5];
  const float* b_in      = (const float*)d_in[6];
  const float* w_out     = (const float*)d_in[7];
  const float* b_out     = (const float*)d_in[8];
  const float* w_rel     = (const float*)d_in[9];
  const float* b_rel     = (const float*)d_in[10];
  float* out = (float*)d_out;

  ushort_t* qbf    = (ushort_t*)d_ws;           // 6144*1024
  ushort_t* winbf  = qbf + 6291456;             // 3072*1024
  ushort_t* woutbf = winbf + 3145728;           // 1024*1024
  ushort_t* relwbf = woutbf + 1048576;          // 512*1024
  ushort_t* Qb     = relwbf + 524288;           // 64*1536*64
  ushort_t* Kbuf   = Qb + 6291456;
  ushort_t* Vtb    = Kbuf + 6291456;
  float*    VM     = (float*)(Vtb + 6291456);   // 6144*512 fp32
  ushort_t* AT     = (ushort_t*)(VM + 3145728); // 6144*1024

  // fp32 -> bf16
  {
    int n4;
    n4 = 6291456 / 4; cvt_kernel<<<(n4 + 255) / 256, 256, 0, stream>>>(query, qbf, n4);
    n4 = 3145728 / 4; cvt_kernel<<<(n4 + 255) / 256, 256, 0, stream>>>(w_in, winbf, n4);
    n4 = 1048576 / 4; cvt_kernel<<<(n4 + 255) / 256, 256, 0, stream>>>(w_out, woutbf, n4);
    n4 = 524288 / 4;  cvt_kernel<<<(n4 + 255) / 256, 256, 0, stream>>>(w_rel, relwbf, n4);
  }

  // in-projection -> Q/K/Vt
  gemm_bt<0><<<dim3(24, 48), 256, 0, stream>>>(qbf, winbf, b_in, nullptr,
                                               Qb, Kbuf, Vtb, MROWS, 3072, 1024);
  // relative-value table VM
  gemm_bt<1><<<dim3(4, 48), 256, 0, stream>>>(qbf, relwbf, b_rel, VM,
                                              nullptr, nullptr, nullptr, MROWS, 512, 1024);
  // fused attention (main + 2 ngram streams)
  attn_kernel<<<dim3(32, 64, 3), 256, 0, stream>>>(Qb, Kbuf, Vtb, VM, ib_main, ib_rel,
                                                   mask_main, mask_ng, AT);
  // out-projection
  gemm_bt<2><<<dim3(8, 48), 256, 0, stream>>>(AT, woutbf, b_out, out,
                                              nullptr, nullptr, nullptr, MROWS, 1024, 1024);
}